// Round 1
// baseline (293.243 us; speedup 1.0000x reference)
//
#include <hip/hip_runtime.h>
#include <hip/hip_bf16.h>
#include <math.h>

// Problem constants
constexpr int B = 32, D = 256, H = 32, W = 32;
constexpr int N = B * H * W;      // 32768 rows
constexpr int K = 1024;           // codebook entries

// Output layout (fp32 elements, concatenated in reference return order)
constexpr int OFF_Q    = 0;                       // quantized_st: 8388608
constexpr int OFF_LOSS = 8388608;                 // scalar
constexpr int OFF_PERP = 8388609;                 // scalar
constexpr int OFF_IDX  = 8388610;                 // 32768 (indices as float)
constexpr int OFF_DIST = 8421378;                 // 33554432  (NOTE: only 8B-aligned)

// ---------------- znorm: ||z_n||^2 ----------------
// z layout (b, d, h, w): z_flat[n][c] = z[(b*256+c)*1024 + r], n = b*1024 + r
__global__ __launch_bounds__(256) void znorm_kernel(const float* __restrict__ z,
                                                    float* __restrict__ znorm) {
    int n = blockIdx.x * 256 + threadIdx.x;
    int b = n >> 10, r = n & 1023;
    const float* p = z + (size_t)b * D * 1024 + r;
    float s = 0.f;
    #pragma unroll 8
    for (int c = 0; c < D; ++c) {
        float v = p[(size_t)c * 1024];
        s += v * v;
    }
    znorm[n] = s;
}

// ---------------- cnorm: ||c_k||^2 (wave per row) ----------------
__global__ __launch_bounds__(256) void cnorm_kernel(const float* __restrict__ cb,
                                                    float* __restrict__ cnorm) {
    int row = blockIdx.x * 4 + (threadIdx.x >> 6);
    int lane = threadIdx.x & 63;
    float4 v = *(const float4*)(cb + (size_t)row * D + lane * 4);
    float s = v.x * v.x + v.y * v.y + v.z * v.z + v.w * v.w;
    #pragma unroll
    for (int off = 32; off; off >>= 1) s += __shfl_down(s, off, 64);
    if (lane == 0) cnorm[row] = s;
}

// ---------------- distances GEMM ----------------
// dist[n][k] = znorm[n] + cnorm[k] - 2 * dot(z_flat[n], cb[k])
// 64x64 tile per block, 256 threads, 4x4 micro-tile, inner chunks of 16 c's.
__global__ __launch_bounds__(256) void dist_gemm(const float* __restrict__ z,
                                                 const float* __restrict__ cb,
                                                 const float* __restrict__ znorm,
                                                 const float* __restrict__ cnorm,
                                                 float* __restrict__ dist) {
    __shared__ float As[16][64];   // [c][n]
    __shared__ float Bs[16][68];   // [c][k], padded row (68 words, 272B = 16B mult)

    int t  = threadIdx.x;
    int k0 = blockIdx.x * 64;
    int n0 = blockIdx.y * 64;
    int b  = n0 >> 10;
    int r0 = n0 & 1023;
    const float* zbase = z + (size_t)b * D * 1024 + r0;

    // A staging: thread loads one float4.  cA = t>>4 (0..15), nnA = (t&15)*4
    int cA = t >> 4, nnA = (t & 15) * 4;
    // B staging: cB = (t&3)*4, kkB = t>>2 (0..63)
    int cB = (t & 3) * 4, kkB = t >> 2;

    int tn = (t & 15) * 4;   // micro-tile n offset
    int tk = (t >> 4) * 4;   // micro-tile k offset

    float acc[4][4] = {};

    for (int c0 = 0; c0 < D; c0 += 16) {
        float4 av = *(const float4*)(zbase + (size_t)(c0 + cA) * 1024 + nnA);
        *(float4*)&As[cA][nnA] = av;

        float4 bv = *(const float4*)(cb + (size_t)(k0 + kkB) * D + c0 + cB);
        Bs[cB + 0][kkB] = bv.x;
        Bs[cB + 1][kkB] = bv.y;
        Bs[cB + 2][kkB] = bv.z;
        Bs[cB + 3][kkB] = bv.w;

        __syncthreads();
        #pragma unroll
        for (int c = 0; c < 16; ++c) {
            float4 a  = *(const float4*)&As[c][tn];
            float4 bb = *(const float4*)&Bs[c][tk];
            acc[0][0] += a.x * bb.x; acc[0][1] += a.x * bb.y;
            acc[0][2] += a.x * bb.z; acc[0][3] += a.x * bb.w;
            acc[1][0] += a.y * bb.x; acc[1][1] += a.y * bb.y;
            acc[1][2] += a.y * bb.z; acc[1][3] += a.y * bb.w;
            acc[2][0] += a.z * bb.x; acc[2][1] += a.z * bb.y;
            acc[2][2] += a.z * bb.z; acc[2][3] += a.z * bb.w;
            acc[3][0] += a.w * bb.x; acc[3][1] += a.w * bb.y;
            acc[3][2] += a.w * bb.z; acc[3][3] += a.w * bb.w;
        }
        __syncthreads();
    }

    float cn[4];
    #pragma unroll
    for (int l = 0; l < 4; ++l) cn[l] = cnorm[k0 + tk + l];
    #pragma unroll
    for (int j = 0; j < 4; ++j) {
        float zn = znorm[n0 + tn + j];
        float v0 = zn + cn[0] - 2.f * acc[j][0];
        float v1 = zn + cn[1] - 2.f * acc[j][1];
        float v2 = zn + cn[2] - 2.f * acc[j][2];
        float v3 = zn + cn[3] - 2.f * acc[j][3];
        float* p = dist + (size_t)(n0 + tn + j) * K + k0 + tk;
        // dist base only 8B-aligned -> float2 stores
        *(float2*)(p + 0) = make_float2(v0, v1);
        *(float2*)(p + 2) = make_float2(v2, v3);
    }
}

// ---------------- argmin (wave per row) ----------------
__global__ __launch_bounds__(256) void argmin_kernel(const float* __restrict__ dist,
                                                     int* __restrict__ idx_i,
                                                     float* __restrict__ out_idx,
                                                     int* __restrict__ hist) {
    int n = blockIdx.x * 4 + (threadIdx.x >> 6);
    int lane = threadIdx.x & 63;
    const float* row = dist + (size_t)n * K;

    float minv = INFINITY;
    int mini = 0;
    #pragma unroll
    for (int j = 0; j < 8; ++j) {                 // 8 chunks of 128 (float2/lane)
        int base = j * 128 + lane * 2;
        float2 v = *(const float2*)(row + base);  // 8B-aligned ok
        if (v.x < minv) { minv = v.x; mini = base; }
        if (v.y < minv) { minv = v.y; mini = base + 1; }
    }
    #pragma unroll
    for (int off = 32; off; off >>= 1) {
        float ov = __shfl_down(minv, off, 64);
        int   oi = __shfl_down(mini, off, 64);
        if (ov < minv || (ov == minv && oi < mini)) { minv = ov; mini = oi; }
    }
    if (lane == 0) {
        idx_i[n] = mini;
        out_idx[n] = (float)mini;
        atomicAdd(&hist[mini], 1);
    }
}

// ---------------- gather + quantized output + MSE partials ----------------
__global__ __launch_bounds__(256) void gather_kernel(const float* __restrict__ z,
                                                     const float* __restrict__ cb,
                                                     const int* __restrict__ idx_i,
                                                     float* __restrict__ out_q,
                                                     float* __restrict__ mse_partial) {
    int n = blockIdx.x * 256 + threadIdx.x;
    int b = n >> 10, r = n & 1023;
    const float* zp = z + (size_t)b * D * 1024 + r;
    float* qp = out_q + (size_t)b * D * 1024 + r;
    const float* crow = cb + (size_t)idx_i[n] * D;

    float s = 0.f;
    for (int c = 0; c < D; c += 4) {
        float4 zq4 = *(const float4*)(crow + c);
        float zq[4] = {zq4.x, zq4.y, zq4.z, zq4.w};
        #pragma unroll
        for (int m = 0; m < 4; ++m) {
            float zv = zp[(size_t)(c + m) * 1024];
            float d = zq[m] - zv;
            qp[(size_t)(c + m) * 1024] = zv + d;   // z + (zq - z), matches ref fp ops
            s += d * d;
        }
    }
    __shared__ float red[256];
    red[threadIdx.x] = s;
    __syncthreads();
    #pragma unroll
    for (int off = 128; off; off >>= 1) {
        if (threadIdx.x < off) red[threadIdx.x] += red[threadIdx.x + off];
        __syncthreads();
    }
    if (threadIdx.x == 0) mse_partial[blockIdx.x] = red[0];
}

// ---------------- finalize: loss + perplexity ----------------
__global__ __launch_bounds__(1024) void finalize_kernel(const int* __restrict__ hist,
                                                        const float* __restrict__ mse_partial,
                                                        float* __restrict__ out) {
    __shared__ float red[1024];
    int t = threadIdx.x;
    float p = (float)hist[t] * (1.0f / (float)N);
    red[t] = p * logf(p + 1e-10f);
    __syncthreads();
    #pragma unroll
    for (int off = 512; off; off >>= 1) {
        if (t < off) red[t] += red[t + off];
        __syncthreads();
    }
    float ent = red[0];          // valid after reduction (read by all, but only t0 uses)
    __syncthreads();
    red[t] = (t < 128) ? mse_partial[t] : 0.f;
    __syncthreads();
    #pragma unroll
    for (int off = 512; off; off >>= 1) {
        if (t < off) red[t] += red[t + off];
        __syncthreads();
    }
    if (t == 0) {
        float mse = red[0] / (float)((size_t)N * D);
        out[OFF_LOSS] = 1.25f * mse;     // BETA*mse + mse
        out[OFF_PERP] = expf(-ent);
    }
}

extern "C" void kernel_launch(void* const* d_in, const int* in_sizes, int n_in,
                              void* d_out, int out_size, void* d_ws, size_t ws_size,
                              hipStream_t stream) {
    const float* z  = (const float*)d_in[0];
    const float* cb = (const float*)d_in[1];
    float* out = (float*)d_out;

    float* ws          = (float*)d_ws;
    float* znorm       = ws;                      // N
    float* cnorm       = ws + N;                  // K
    float* mse_partial = ws + N + K;              // 128
    int*   hist        = (int*)(ws + N + K + 128);  // K
    int*   idx_i       = hist + K;                // N

    hipMemsetAsync(hist, 0, K * sizeof(int), stream);

    znorm_kernel<<<N / 256, 256, 0, stream>>>(z, znorm);
    cnorm_kernel<<<K / 4, 256, 0, stream>>>(cb, cnorm);
    dist_gemm<<<dim3(K / 64, N / 64), 256, 0, stream>>>(z, cb, znorm, cnorm, out + OFF_DIST);
    argmin_kernel<<<N / 4, 256, 0, stream>>>(out + OFF_DIST, idx_i, out + OFF_IDX, hist);
    gather_kernel<<<N / 256, 256, 0, stream>>>(z, cb, idx_i, out + OFF_Q, mse_partial);
    finalize_kernel<<<1, 1024, 0, stream>>>(hist, mse_partial, out);
}

// Round 4
// 129.270 us; speedup vs baseline: 2.2684x; 2.2684x over previous
//
#include <hip/hip_runtime.h>
#include <hip/hip_bf16.h>
#include <math.h>

constexpr int D = 256;
constexpr int N = 32768;    // 32 * 32 * 32
constexpr int K = 1024;
constexpr float MARGIN = 1.5e-3f;

constexpr int OFF_Q    = 0;
constexpr int OFF_LOSS = 8388608;
constexpr int OFF_PERP = 8388609;
constexpr int OFF_IDX  = 8388610;
constexpr int OFF_DIST = 8421378;  // 8B-aligned only

using f32x4 = __attribute__((ext_vector_type(4))) float;
using s16x8 = __attribute__((ext_vector_type(8))) short;
using u16x8 = __attribute__((ext_vector_type(8))) unsigned short;
using u16x4 = __attribute__((ext_vector_type(4))) unsigned short;

#define GLOAD_LDS16(g, l)                                                     \
    __builtin_amdgcn_global_load_lds(                                         \
        (const __attribute__((address_space(1))) void*)(g),                   \
        (__attribute__((address_space(3))) void*)(l), 16, 0, 0)

__device__ __forceinline__ unsigned short bf16_bits(float v) {
    __hip_bfloat16 h = __float2bfloat16(v);
    return *(unsigned short*)&h;
}

// ---- split_z: transpose z -> z_t (fp32 N x 256), A (bf16 N x 256), znorm ----
// z[b][d][r] -> z_t[n][d], n = b*1024 + r. Block: one 64-r stripe of one b,
// loops over 4 d-tiles of 64.
__global__ __launch_bounds__(256) void split_z_kernel(const float* __restrict__ z,
                                                      unsigned short* __restrict__ A,
                                                      float* __restrict__ z_t,
                                                      float* __restrict__ znorm) {
    __shared__ float tile[64][65];
    __shared__ float znp[64][4];
    int t = threadIdx.x;
    int r0 = blockIdx.x * 64;
    int b  = blockIdx.y;
    const float* zb = z + (size_t)b * D * 1024;
    int rr4 = (t & 15) * 4;
    int rr = t >> 2, chunk = t & 3;
    size_t n = (size_t)b * 1024 + r0 + rr;
    float zacc = 0.f;

    for (int dblk = 0; dblk < 4; ++dblk) {
        int d0 = dblk * 64;
        if (dblk) __syncthreads();
        #pragma unroll
        for (int i = 0; i < 4; ++i) {
            int di = i * 16 + (t >> 4);
            float4 v = *(const float4*)(zb + (size_t)(d0 + di) * 1024 + r0 + rr4);
            *(float4*)&tile[di][rr4] = v;
        }
        __syncthreads();

        unsigned short hbuf[16];
        float fbuf[16];
        #pragma unroll
        for (int i = 0; i < 16; ++i) {
            float v = tile[chunk * 16 + i][rr];
            fbuf[i] = v;
            hbuf[i] = bf16_bits(v);
            zacc += v * v;
        }
        unsigned short* pa = A + n * 256 + d0 + chunk * 16;
        *(u16x8*)(pa + 0) = *(u16x8*)&hbuf[0];
        *(u16x8*)(pa + 8) = *(u16x8*)&hbuf[8];
        float* pz = z_t + n * 256 + d0 + chunk * 16;
        #pragma unroll
        for (int q = 0; q < 4; ++q)
            *(float4*)(pz + q * 4) = *(float4*)&fbuf[q * 4];
    }
    znp[rr][chunk] = zacc;
    __syncthreads();
    if (t < 64) {
        float s = znp[t][0] + znp[t][1] + znp[t][2] + znp[t][3];
        znorm[(size_t)b * 1024 + r0 + t] = s;
    }
}

// ---- split_cb: bf16 codebook + cnorm (one wave per row) ----
__global__ __launch_bounds__(256) void split_cb_kernel(const float* __restrict__ cb,
                                                       unsigned short* __restrict__ Bb,
                                                       float* __restrict__ cnorm) {
    int k = blockIdx.x * 4 + (threadIdx.x >> 6);
    int lane = threadIdx.x & 63;
    float4 v = *(const float4*)(cb + (size_t)k * D + lane * 4);
    unsigned short hb[4] = {bf16_bits(v.x), bf16_bits(v.y), bf16_bits(v.z), bf16_bits(v.w)};
    *(u16x4*)(Bb + (size_t)k * 256 + lane * 4) = *(u16x4*)&hb[0];
    float s = v.x * v.x + v.y * v.y + v.z * v.z + v.w * v.w;
    #pragma unroll
    for (int off = 32; off; off >>= 1) s += __shfl_down(s, off, 64);
    if (lane == 0) cnorm[k] = s;
}

// ---- approx distance GEMM: plain bf16, 128x128 tile, 4 K-steps ----
__global__ __launch_bounds__(256) void dist_gemm_mfma(const unsigned short* __restrict__ A,
                                                      const unsigned short* __restrict__ Bb,
                                                      const float* __restrict__ znorm,
                                                      const float* __restrict__ cnorm,
                                                      float* __restrict__ dist) {
    __shared__ unsigned short As[128 * 64];
    __shared__ unsigned short Bs[128 * 64];

    int t = threadIdx.x;
    int l = t & 63;
    int w = t >> 6;
    int k0 = blockIdx.x * 128;
    int n0 = blockIdx.y * 128;

    int srow = t >> 3;
    int scol = (t & 7) * 8;
    const unsigned short* Ab = A + ((size_t)(n0 + srow)) * 256 + scol;
    const unsigned short* Bbp = Bb + ((size_t)(k0 + srow)) * 256 + scol;
    unsigned short* AsBase = As + t * 8;
    unsigned short* BsBase = Bs + t * 8;

    f32x4 acc[4][4];
    #pragma unroll
    for (int i = 0; i < 4; ++i)
        #pragma unroll
        for (int j = 0; j < 4; ++j) acc[i][j] = (f32x4){0.f, 0.f, 0.f, 0.f};

    int wr = w >> 1, wc = w & 1;
    int aRowBase = wr * 64 + (l & 15);
    int bRowBase = wc * 64 + (l & 15);
    int kLane = (l >> 4) * 8;

    #pragma unroll
    for (int kt = 0; kt < 4; ++kt) {
        int col = kt * 64;
        #pragma unroll
        for (int pass = 0; pass < 4; ++pass) {
            GLOAD_LDS16(Ab + (size_t)pass * 32 * 256 + col, AsBase + pass * 2048);
            GLOAD_LDS16(Bbp + (size_t)pass * 32 * 256 + col, BsBase + pass * 2048);
        }
        __syncthreads();

        #pragma unroll
        for (int kk = 0; kk < 64; kk += 32) {
            s16x8 af[4], bf[4];
            #pragma unroll
            for (int mf = 0; mf < 4; ++mf)
                af[mf] = *(const s16x8*)&As[(aRowBase + mf * 16) * 64 + kk + kLane];
            #pragma unroll
            for (int nf = 0; nf < 4; ++nf)
                bf[nf] = *(const s16x8*)&Bs[(bRowBase + nf * 16) * 64 + kk + kLane];
            #pragma unroll
            for (int mf = 0; mf < 4; ++mf)
                #pragma unroll
                for (int nf = 0; nf < 4; ++nf)
                    acc[mf][nf] = __builtin_amdgcn_mfma_f32_16x16x32_bf16(
                        af[mf], bf[nf], acc[mf][nf], 0, 0, 0);
        }
        if (kt < 3) __syncthreads();
    }

    int colBase = k0 + wc * 64 + (l & 15);
    int rowBase = n0 + wr * 64 + (l >> 4) * 4;
    float cn[4];
    #pragma unroll
    for (int nf = 0; nf < 4; ++nf) cn[nf] = cnorm[colBase + nf * 16];
    #pragma unroll
    for (int mf = 0; mf < 4; ++mf) {
        #pragma unroll
        for (int r = 0; r < 4; ++r) {
            int n = rowBase + mf * 16 + r;
            float zn = znorm[n];
            float* p = dist + (size_t)n * K;
            #pragma unroll
            for (int nf = 0; nf < 4; ++nf)
                p[colBase + nf * 16] = zn + cn[nf] - 2.0f * acc[mf][nf][r];
        }
    }
}

// ---- argmin with exact fp32 resolve of near-tie candidates ----
__global__ __launch_bounds__(256) void argmin_resolve_kernel(const float* __restrict__ dist,
                                                             const float* __restrict__ z_t,
                                                             const float* __restrict__ cb,
                                                             const float* __restrict__ znorm,
                                                             const float* __restrict__ cnorm,
                                                             int* __restrict__ idx_i,
                                                             float* __restrict__ out_idx,
                                                             int* __restrict__ hist) {
    int n = blockIdx.x * 4 + (threadIdx.x >> 6);
    int lane = threadIdx.x & 63;
    const float* row = dist + (size_t)n * K;

    float2 v[8];
    float minv = INFINITY;
    #pragma unroll
    for (int j = 0; j < 8; ++j) {
        v[j] = *(const float2*)(row + j * 128 + lane * 2);
        minv = fminf(minv, fminf(v[j].x, v[j].y));
    }
    #pragma unroll
    for (int off = 1; off < 64; off <<= 1)
        minv = fminf(minv, __shfl_xor(minv, off, 64));
    float thresh = minv + MARGIN;

    unsigned long long mx[8], my[8];
    int cnt = 0;
    #pragma unroll
    for (int j = 0; j < 8; ++j) {
        mx[j] = __ballot(v[j].x <= thresh);
        my[j] = __ballot(v[j].y <= thresh);
        cnt += __popcll(mx[j]) + __popcll(my[j]);
    }

    int besti = 0;
    if (cnt == 1) {
        #pragma unroll
        for (int j = 0; j < 8; ++j) {
            if (mx[j]) besti = j * 128 + 2 * __builtin_ctzll(mx[j]);
            if (my[j]) besti = j * 128 + 2 * __builtin_ctzll(my[j]) + 1;
        }
    } else {
        // exact fp32 recompute for all candidates (wave-cooperative)
        float4 zr = *(const float4*)(z_t + (size_t)n * 256 + lane * 4);
        float zn = znorm[n];
        float bestv = INFINITY;
        besti = 0x7fffffff;
        for (int j = 0; j < 8; ++j) {
            #pragma unroll
            for (int half = 0; half < 2; ++half) {
                unsigned long long m = half ? my[j] : mx[j];
                while (m) {
                    int lb = __builtin_ctzll(m);
                    m &= m - 1;
                    int k = j * 128 + 2 * lb + half;
                    float4 cr = *(const float4*)(cb + (size_t)k * D + lane * 4);
                    float s = zr.x * cr.x + zr.y * cr.y + zr.z * cr.z + zr.w * cr.w;
                    #pragma unroll
                    for (int off = 1; off < 64; off <<= 1)
                        s += __shfl_xor(s, off, 64);
                    float dd = zn + cnorm[k] - 2.0f * s;
                    if (dd < bestv || (dd == bestv && k < besti)) { bestv = dd; besti = k; }
                }
            }
        }
    }

    if (lane == 0) {
        idx_i[n] = besti;
        out_idx[n] = (float)besti;
        atomicAdd(&hist[besti], 1);
    }
}

// ---- gather + quantized + MSE partials ----
__global__ __launch_bounds__(256) void gather_kernel(const float* __restrict__ z,
                                                     const float* __restrict__ cb,
                                                     const int* __restrict__ idx_i,
                                                     float* __restrict__ out_q,
                                                     float* __restrict__ mse_partial) {
    int n = blockIdx.x * 256 + threadIdx.x;
    int b = n >> 10, r = n & 1023;
    const float* zp = z + (size_t)b * D * 1024 + r;
    float* qp = out_q + (size_t)b * D * 1024 + r;
    const float* crow = cb + (size_t)idx_i[n] * D;

    float s = 0.f;
    for (int c = 0; c < D; c += 4) {
        float4 zq4 = *(const float4*)(crow + c);
        float zq[4] = {zq4.x, zq4.y, zq4.z, zq4.w};
        #pragma unroll
        for (int m = 0; m < 4; ++m) {
            float zv = zp[(size_t)(c + m) * 1024];
            float d = zq[m] - zv;
            qp[(size_t)(c + m) * 1024] = zv + d;
            s += d * d;
        }
    }
    __shared__ float red[256];
    red[threadIdx.x] = s;
    __syncthreads();
    #pragma unroll
    for (int off = 128; off; off >>= 1) {
        if (threadIdx.x < off) red[threadIdx.x] += red[threadIdx.x + off];
        __syncthreads();
    }
    if (threadIdx.x == 0) mse_partial[blockIdx.x] = red[0];
}

// ---- finalize ----
__global__ __launch_bounds__(1024) void finalize_kernel(const int* __restrict__ hist,
                                                        const float* __restrict__ mse_partial,
                                                        float* __restrict__ out) {
    __shared__ float red[1024];
    int t = threadIdx.x;
    float p = (float)hist[t] * (1.0f / (float)N);
    red[t] = p * logf(p + 1e-10f);
    __syncthreads();
    #pragma unroll
    for (int off = 512; off; off >>= 1) {
        if (t < off) red[t] += red[t + off];
        __syncthreads();
    }
    float ent = red[0];
    __syncthreads();
    red[t] = (t < 128) ? mse_partial[t] : 0.f;
    __syncthreads();
    #pragma unroll
    for (int off = 512; off; off >>= 1) {
        if (t < off) red[t] += red[t + off];
        __syncthreads();
    }
    if (t == 0) {
        float mse = red[0] / (float)((size_t)N * D);
        out[OFF_LOSS] = 1.25f * mse;
        out[OFF_PERP] = expf(-ent);
    }
}

extern "C" void kernel_launch(void* const* d_in, const int* in_sizes, int n_in,
                              void* d_out, int out_size, void* d_ws, size_t ws_size,
                              hipStream_t stream) {
    const float* z  = (const float*)d_in[0];
    const float* cb = (const float*)d_in[1];
    float* out = (float*)d_out;

    char* wsb = (char*)d_ws;
    unsigned short* A  = (unsigned short*)wsb;                         // 16.78 MB
    float* z_t         = (float*)(wsb + (size_t)N * 256 * 2);          // 33.55 MB
    unsigned short* Bb = (unsigned short*)(wsb + (size_t)N * 256 * 6); // 0.52 MB
    float* znorm       = (float*)(wsb + (size_t)N * 256 * 6 + (size_t)K * 256 * 2);
    float* cnorm       = znorm + N;
    float* mse_partial = cnorm + K;
    int* hist          = (int*)(mse_partial + 128);
    int* idx_i         = hist + K;

    hipMemsetAsync(hist, 0, K * sizeof(int), stream);

    split_z_kernel<<<dim3(16, 32), 256, 0, stream>>>(z, A, z_t, znorm);
    split_cb_kernel<<<K / 4, 256, 0, stream>>>(cb, Bb, cnorm);
    dist_gemm_mfma<<<dim3(K / 128, N / 128), 256, 0, stream>>>(A, Bb, znorm, cnorm,
                                                               out + OFF_DIST);
    argmin_resolve_kernel<<<N / 4, 256, 0, stream>>>(out + OFF_DIST, z_t, cb, znorm, cnorm,
                                                     idx_i, out + OFF_IDX, hist);
    gather_kernel<<<N / 256, 256, 0, stream>>>(z, cb, idx_i, out + OFF_Q, mse_partial);
    finalize_kernel<<<1, 1024, 0, stream>>>(hist, mse_partial, out);
}